// Round 4
// baseline (443.777 us; speedup 1.0000x reference)
//
#include <hip/hip_runtime.h>
#include <hip/hip_bf16.h>

// Problem constants (FEDformerEncoder): BS=32 CNT=128 W=2048 P=1024 E=8 K=25 L=2
#define BSZ 32
#define CNTS 128
#define WD 2048
#define PD 1024
#define ED 8
#define KSZ 25
#define LN 2
#define MROWS (BSZ*CNTS)   // 4096
#define QKVN (3*PD)        // 3072
#define NWL (PD*WD)        // 2M elements per weight tensor per layer

typedef _Float16 f16;
typedef __attribute__((ext_vector_type(8))) _Float16 f16x8;  // 8 f16 = 4 VGPRs
typedef __attribute__((ext_vector_type(4))) float f32x4;
typedef __attribute__((ext_vector_type(2))) float f32x2;

#define PI_F 3.14159265358979323846f
// LDS physical index padding for the FFT (+1 float2 per 32 elements)
#define PAD(a) ((a) + ((a) >> 5))

// ---------------------------------------------------------------------------
// Per-layer weight conversion, one dispatch: wq|wk|wv -> wqkv16 packed, wo -> wo16.
// ---------------------------------------------------------------------------
__global__ __launch_bounds__(256) void cvt_layer(
    const float* __restrict__ wq, const float* __restrict__ wk,
    const float* __restrict__ wv, const float* __restrict__ wo,
    f16* __restrict__ wqkv16, f16* __restrict__ wo16)
{
    const int i = (blockIdx.x * 256 + threadIdx.x) * 4;
    const float* src;
    f16* dst;
    if (i < 3*NWL) {
        dst = wqkv16 + i;
        src = (i < NWL) ? wq + i : (i < 2*NWL) ? wk + (i - NWL) : wv + (i - 2*NWL);
    } else {
        dst = wo16 + (i - 3*NWL);
        src = wo + (i - 3*NWL);
    }
    const float4 v = *(const float4*)src;
    f16 o[4];
    o[0] = (f16)v.x; o[1] = (f16)v.y; o[2] = (f16)v.z; o[3] = (f16)v.w;
    *(ushort4*)dst = *(const ushort4*)o;
}

// ---------------------------------------------------------------------------
// MoE conv: mean over E of conv1d(x, w_e)+b_e == conv1d(x, mean_e w_e)+mean_e b_e
// ---------------------------------------------------------------------------
template<typename IT>
__global__ __launch_bounds__(256) void conv_moe(
    const IT* __restrict__ xin,      // [4096, 2048]
    const float* __restrict__ cw,    // [E, K] layer slice
    const float* __restrict__ cb,    // [E]
    f16* __restrict__ xo)            // [4096, 2048] f16
{
    __shared__ float srow[WD];
    __shared__ float swb[KSZ];
    __shared__ float sbb;
    const int tid = threadIdx.x;
    const size_t row = blockIdx.x;
    if (tid < KSZ) {
        float s = 0.f;
        for (int e = 0; e < ED; ++e) s += cw[e*KSZ + tid];
        swb[tid] = s * (1.f/ED);
    }
    if (tid == 32) {
        float s = 0.f;
        for (int e = 0; e < ED; ++e) s += cb[e];
        sbb = s * (1.f/ED);
    }
    const IT* xr = xin + row*WD;
    for (int i = tid; i < WD; i += 256) srow[i] = (float)xr[i];
    __syncthreads();
    const float bb = sbb;
    for (int t0 = 0; t0 < WD; t0 += 256) {
        const int t = t0 + tid;
        float acc = bb;
        #pragma unroll
        for (int k = 0; k < KSZ; ++k) {
            const int idx = t + k - (KSZ/2);
            const float xv = (idx >= 0 && idx < WD) ? srow[idx] : 0.f;
            acc = fmaf(xv, swb[k], acc);
        }
        xo[row*WD + t] = (f16)acc;
    }
}

// ---------------------------------------------------------------------------
// f16 MFMA GEMM, B^T layout, 128x128 tile (verified m97-class structure).
// Kept for the out-projection GEMM (M=4096, K=1024, N=2048 -> 512 blocks).
// ---------------------------------------------------------------------------
template<typename OT>
__global__ __launch_bounds__(256, 2) void gemm_f16(
    const f16* __restrict__ A,   // [M, K]
    const f16* __restrict__ B,   // [N, K]
    const float* __restrict__ c0, const float* __restrict__ c1, const float* __restrict__ c2,
    OT* __restrict__ out,        // [M, N]
    const int K, const int N)
{
    __shared__ f16 sA[128*64];
    __shared__ f16 sB[128*64];
    const int tid  = threadIdx.x;
    const int m0   = blockIdx.x * 128;
    const int n0   = blockIdx.y * 128;
    const int lane = tid & 63;
    const int wave = tid >> 6;
    const int wm   = (wave >> 1) * 64;
    const int wn   = (wave & 1) * 64;
    const int quad = lane >> 4;
    const int r16  = lane & 15;

    f32x4 acc[4][4] = {};

    int aoff[4];
    #pragma unroll
    for (int t = 0; t < 4; ++t) {
        const int s = tid + 256*t;
        const int row = s >> 3;
        const int sc8 = ((s & 7) ^ (row & 7)) * 8;
        aoff[t] = row * K + sc8;
    }

    int aBase[4], aXor[4], bBase[4], bXor[4];
    #pragma unroll
    for (int i = 0; i < 4; ++i) {
        const int ra = wm + i*16 + r16;
        aBase[i] = ra << 3; aXor[i] = ra & 7;
        const int rb = wn + i*16 + r16;
        bBase[i] = rb << 3; bXor[i] = rb & 7;
    }

    const size_t mK = (size_t)m0 * K;
    const size_t nK = (size_t)n0 * K;

    for (int kb = 0; kb < K; kb += 64) {
        #pragma unroll
        for (int t = 0; t < 4; ++t) {
            const int s = tid + 256*t;
            __builtin_amdgcn_global_load_lds(
                (const __attribute__((address_space(1))) unsigned int*)(A + mK + aoff[t] + kb),
                (__attribute__((address_space(3))) unsigned int*)&sA[s*8], 16, 0, 0);
            __builtin_amdgcn_global_load_lds(
                (const __attribute__((address_space(1))) unsigned int*)(B + nK + aoff[t] + kb),
                (__attribute__((address_space(3))) unsigned int*)&sB[s*8], 16, 0, 0);
        }
        __syncthreads();

        #pragma unroll
        for (int ks = 0; ks < 2; ++ks) {
            const int c = ks*4 + quad;
            f16x8 af[4], bfm[4];
            #pragma unroll
            for (int i = 0; i < 4; ++i)
                af[i] = *(const f16x8*)&sA[(aBase[i] | (c ^ aXor[i])) * 8];
            #pragma unroll
            for (int j = 0; j < 4; ++j)
                bfm[j] = *(const f16x8*)&sB[(bBase[j] | (c ^ bXor[j])) * 8];
            #pragma unroll
            for (int i = 0; i < 4; ++i)
                #pragma unroll
                for (int j = 0; j < 4; ++j)
                    acc[i][j] = __builtin_amdgcn_mfma_f32_16x16x32_f16(af[i], bfm[j], acc[i][j], 0, 0, 0);
        }
        __syncthreads();
    }

    #pragma unroll
    for (int j = 0; j < 4; ++j) {
        const int col = n0 + wn + j*16 + r16;
        const float bv = (col < 1024) ? c0[col] : (col < 2048) ? c1[col-1024] : c2[col-2048];
        #pragma unroll
        for (int i = 0; i < 4; ++i) {
            #pragma unroll
            for (int r = 0; r < 4; ++r) {
                const int rowg = m0 + wm + i*16 + quad*4 + r;
                out[(size_t)rowg*N + col] = (OT)(acc[i][j][r] + bv);
            }
        }
    }
}

// ---------------------------------------------------------------------------
// QKV GEMM (M=4096, K=2048, N=3072): 128x192 tile, BK=64, 3-DEEP LDS pipeline.
// 512 thr = 8 waves (2m x 4n), per-wave C = 64x48 (4x3 frags, 48 acc VGPRs).
// LDS 120 KiB: sA[3][128x64] + sB[3][192x64], XOR-chunk swizzled (slot s holds
// 16B chunk (s&7)^(row&7) of row s>>3 -> conflict-free ds_read_b128 under the
// global_load_lds linear-destination rule).
// Pipeline: window t computes from buf[t%3] while STAGING tile t+2 into
// buf[(t+2)%3] -> vmcnt lead ~2 windows (covers HBM-miss latency), vmcnt(5)
// steady state (5 loads/thread/tile stay in flight), ONE barrier per window.
// Hazards: buf[(t+2)%3] != {t,t+1 buffers}; its last readers (window t-1)
// retired reads before the barrier that ended window t-1 < stage issue.
// Publication: reads of tile t covered by vmcnt(5) at end of window t-1.
// Grid 32m x 16n = 512 blocks = 2 even rounds over 256 CUs; 2D XCD chunk
// (8m x 8n per XCD, ~10 MB footprint vs 4 MB L2).
// Epilogue: C bounced through LDS (overlay on sB) -> fully coalesced 16B/lane
// stores (fixes the measured 45 MB WRITE_SIZE for a 24 MB output: partial
// 64B-line f16 scatter caused ~2x write amplification).
// ---------------------------------------------------------------------------
__global__ __launch_bounds__(512, 1) void gemmQKV(
    const f16* __restrict__ A,   // [M, K]
    const f16* __restrict__ B,   // [N, K]
    const float* __restrict__ c0, const float* __restrict__ c1, const float* __restrict__ c2,
    f16* __restrict__ out,       // [M, N]
    const int K, const int N)
{
    __shared__ __align__(16) f16 sA[3][128*64];
    __shared__ __align__(16) f16 sB[3][192*64];

    const int tid  = threadIdx.x;
    const int lane = tid & 63;
    const int wave = tid >> 6;
    const int wr   = wave >> 2;          // 0..1 : 64-row block
    const int wc   = wave & 3;           // 0..3 : 48-col block
    const int quad = lane >> 4;
    const int r16  = lane & 15;

    // 2D XCD chunking: grid 32m x 16n = 512; XCD owns 8m x 8n (64 blocks)
    const int orig = blockIdx.x;
    const int xcd  = orig & 7;
    const int loc  = orig >> 3;          // 0..63
    const int mt   = (xcd >> 1) * 8 + (loc & 7);
    const int nt   = (xcd & 1) * 8 + (loc >> 3);
    const int m0   = mt * 128;
    const int n0   = nt * 192;

    f32x4 acc[4][3] = {};

    // staging source offsets: slot s -> row s>>3, chunk (s&7)^(row&7)
    int soffA[2];
    #pragma unroll
    for (int t = 0; t < 2; ++t) {
        const int s = tid + 512*t;
        const int row = s >> 3;
        soffA[t] = row * K + (((s & 7) ^ (row & 7)) * 8);
    }
    int soffB[3];
    #pragma unroll
    for (int t = 0; t < 3; ++t) {
        const int s = tid + 512*t;
        const int row = s >> 3;
        soffB[t] = row * K + (((s & 7) ^ (row & 7)) * 8);
    }

    const f16* Ab = A + (size_t)m0 * K;
    const f16* Bb = B + (size_t)n0 * K;

    #define STAGE_A(BUF, GOFF)                                                    \
      { _Pragma("unroll") for (int t = 0; t < 2; ++t) {                           \
          __builtin_amdgcn_global_load_lds(                                       \
            (const __attribute__((address_space(1))) unsigned int*)(Ab + soffA[t] + (GOFF)), \
            (__attribute__((address_space(3))) unsigned int*)&sA[BUF][(tid + 512*t)*8], \
            16, 0, 0); } }

    #define STAGE_B(BUF, GOFF)                                                    \
      { _Pragma("unroll") for (int t = 0; t < 3; ++t) {                           \
          __builtin_amdgcn_global_load_lds(                                       \
            (const __attribute__((address_space(1))) unsigned int*)(Bb + soffB[t] + (GOFF)), \
            (__attribute__((address_space(3))) unsigned int*)&sB[BUF][(tid + 512*t)*8], \
            16, 0, 0); } }

    #define LDA(BUF, ROW, C) \
      (*(const f16x8*)&sA[BUF][ (((ROW) << 3) | ((C) ^ ((ROW) & 7))) * 8 ])
    #define LDB(BUF, ROW, C) \
      (*(const f16x8*)&sB[BUF][ (((ROW) << 3) | ((C) ^ ((ROW) & 7))) * 8 ])

    #define VMC(n)  asm volatile("s_waitcnt vmcnt(" #n ")" ::: "memory");
    #define BAR()   __builtin_amdgcn_s_barrier();

    // prologue: tile0 -> buf0, tile1 -> buf1; retire tile0 (oldest 5), keep
    // tile1's 5 in flight.
    STAGE_A(0, 0); STAGE_B(0, 0);
    STAGE_A(1, 64); STAGE_B(1, 64);
    VMC(5)
    BAR()

    const int NT = K >> 6;   // 32 K-tiles of 64
    int cur = 0;
    for (int t = 0; t < NT; ++t) {
        const int nx2 = (cur >= 1) ? cur - 1 : cur + 2;   // (t+2)%3

        // stage tile t+2 (issue first: maximum lead)
        if (t < NT-2) {
            const int kb2 = (t + 2) << 6;
            STAGE_A(nx2, kb2);
            STAGE_B(nx2, kb2);
        }

        // ds-read this window's fragments from buf[cur]
        f16x8 af[4][2], bfr[3][2];
        #pragma unroll
        for (int mi = 0; mi < 4; ++mi) {
            const int ra = wr*64 + mi*16 + r16;
            af[mi][0] = LDA(cur, ra, quad);
            af[mi][1] = LDA(cur, ra, 4 + quad);
        }
        #pragma unroll
        for (int j = 0; j < 3; ++j) {
            const int rb = wc*48 + j*16 + r16;
            bfr[j][0] = LDB(cur, rb, quad);
            bfr[j][1] = LDB(cur, rb, 4 + quad);
        }
        asm volatile("s_waitcnt lgkmcnt(0)" ::: "memory");
        __builtin_amdgcn_sched_barrier(0);

        __builtin_amdgcn_s_setprio(1);
        #pragma unroll
        for (int mi = 0; mi < 4; ++mi)
            #pragma unroll
            for (int j = 0; j < 3; ++j)
                acc[mi][j] = __builtin_amdgcn_mfma_f32_16x16x32_f16(af[mi][0], bfr[j][0], acc[mi][j], 0, 0, 0);
        #pragma unroll
        for (int mi = 0; mi < 4; ++mi)
            #pragma unroll
            for (int j = 0; j < 3; ++j)
                acc[mi][j] = __builtin_amdgcn_mfma_f32_16x16x32_f16(af[mi][1], bfr[j][1], acc[mi][j], 0, 0, 0);
        __builtin_amdgcn_s_setprio(0);

        // publish tile t+1 for next window (retire everything older than the
        // newest in-flight stage batch); drain at the pipeline tail.
        if (t < NT-2) { VMC(5) } else { VMC(0) }
        BAR()

        cur = (cur == 2) ? 0 : cur + 1;
    }

    // -------- epilogue: bounce C through LDS, store coalesced 16B/lane --------
    // bounce buffer overlays sB: [128][200] f16 (stride 200 for bank spread)
    f16* bounce = (f16*)&sB[0][0];
    #pragma unroll
    for (int j = 0; j < 3; ++j) {
        const int colt = wc*48 + j*16 + r16;
        const int col  = n0 + colt;
        const float bv = (col < 1024) ? c0[col] : (col < 2048) ? c1[col-1024] : c2[col-2048];
        #pragma unroll
        for (int mi = 0; mi < 4; ++mi) {
            #pragma unroll
            for (int r = 0; r < 4; ++r) {
                const int rowt = wr*64 + mi*16 + quad*4 + r;
                bounce[rowt*200 + colt] = (f16)(acc[mi][j][r] + bv);
            }
        }
    }
    BAR()
    // 128 rows x 24 chunks of 8 f16 = 3072 chunks; 6 per thread
    #pragma unroll
    for (int p = 0; p < 6; ++p) {
        const int g   = tid + 512*p;
        const int row = g / 24;
        const int k   = g - row*24;
        const f16x8 v = *(const f16x8*)&bounce[row*200 + k*8];
        *(f16x8*)&out[(size_t)(m0 + row)*N + n0 + k*8] = v;
    }

    #undef STAGE_A
    #undef STAGE_B
    #undef LDA
    #undef LDB
    #undef VMC
    #undef BAR
}

// ---------------------------------------------------------------------------
// Stockham radix-4 DIF FFT, 1024 points, 256 threads, interleaved f32x2 in LDS
// ---------------------------------------------------------------------------
__device__ inline void fft1024r4(f32x2* x, f32x2* y, const int tid)
{
    f32x2* src = x;
    f32x2* dst = y;
    #pragma unroll
    for (int st = 0; st < 5; ++st) {
        const int ls = 2*st;
        const int s  = 1 << ls;
        const int p  = tid >> ls;
        const int q  = tid & (s - 1);
        const float invn = 1.f / (float)(1024 >> ls);
        const f32x2 a = src[PAD(tid)];
        const f32x2 b = src[PAD(tid + 256)];
        const f32x2 c = src[PAD(tid + 512)];
        const f32x2 d = src[PAD(tid + 768)];
        float ws, wc;
        __sincosf(-2.f*PI_F * (float)p * invn, &ws, &wc);
        const float apcx = a.x + c.x, apcy = a.y + c.y;
        const float amcx = a.x - c.x, amcy = a.y - c.y;
        const float bpdx = b.x + d.x, bpdy = b.y + d.y;
        const float bmdx = b.x - d.x, bmdy = b.y - d.y;
        f32x2 y0; y0.x = apcx + bpdx; y0.y = apcy + bpdy;
        const float t1x = amcx + bmdy, t1y = amcy - bmdx;   // amc - i*bmd
        const float t2x = apcx - bpdx, t2y = apcy - bpdy;
        const float t3x = amcx - bmdy, t3y = amcy + bmdx;   // amc + i*bmd
        const float w2x = wc*wc - ws*ws, w2y = 2.f*wc*ws;
        const float w3x = w2x*wc - w2y*ws, w3y = w2x*ws + w2y*wc;
        f32x2 y1; y1.x = wc*t1x - ws*t1y;   y1.y = wc*t1y + ws*t1x;
        f32x2 y2; y2.x = w2x*t2x - w2y*t2y; y2.y = w2x*t2y + w2y*t2x;
        f32x2 y3; y3.x = w3x*t3x - w3y*t3y; y3.y = w3x*t3y + w3y*t3x;
        const int base = q + ((p * s) << 2);
        dst[PAD(base)]       = y0;
        dst[PAD(base + s)]   = y1;
        dst[PAD(base + 2*s)] = y2;
        dst[PAD(base + 3*s)] = y3;
        __syncthreads();
        f32x2* t = src; src = dst; dst = t;
    }
}

// ---------------------------------------------------------------------------
// FFT-domain attention, two rows per block, packed-real FFTs (f16 in, f16 out)
// ---------------------------------------------------------------------------
__global__ __launch_bounds__(256) void fft_attn2(
    const f16* __restrict__ qkv, f16* __restrict__ outg)
{
    __shared__ f32x2 X[PAD(1023)+1], Y[PAD(1023)+1];
    const int tid = threadIdx.x;
    const size_t row0 = (size_t)blockIdx.x * 2;
    const f16* r1 = qkv + row0*QKVN;        // q1 | k1 | v1
    const f16* r2 = r1 + QKVN;              // q2 | k2 | v2

    f32x2 V1[4], V2[4], S1[4], S2[4];

    // ---- FFT(v1 + i*v2) -> V1, V2 in registers ----
    #pragma unroll
    for (int k = 0; k < 4; ++k) {
        const int i = tid + 256*k;
        f32x2 t; t.x = (float)r1[2048+i]; t.y = (float)r2[2048+i];
        X[PAD(i)] = t;
    }
    __syncthreads();
    fft1024r4(X, Y, tid);
    #pragma unroll
    for (int k = 0; k < 4; ++k) {
        const int f = tid + 256*k;
        const int g = (PD - f) & (PD-1);
        const f32x2 z1 = Y[PAD(f)], z2 = Y[PAD(g)];
        V1[k].x = 0.5f*(z1.x + z2.x); V1[k].y = 0.5f*(z1.y - z2.y);
        V2[k].x = 0.5f*(z1.y + z2.y); V2[k].y = 0.5f*(z2.x - z1.x);
    }

    // ---- FFT(q1 + i*k1) ; S1 = conj(K1*conj(Q1)*V1/32) ----
    #pragma unroll
    for (int k = 0; k < 4; ++k) {
        const int i = tid + 256*k;
        f32x2 t; t.x = (float)r1[i]; t.y = (float)r1[1024+i];
        X[PAD(i)] = t;
    }
    __syncthreads();   // fences the V-split reads of Y above
    fft1024r4(X, Y, tid);
    #pragma unroll
    for (int k = 0; k < 4; ++k) {
        const int f = tid + 256*k;
        const int g = (PD - f) & (PD-1);
        const f32x2 z1 = Y[PAD(f)], z2 = Y[PAD(g)];
        const float Qr = 0.5f*(z1.x + z2.x), Qi = 0.5f*(z1.y - z2.y);
        const float Kr = 0.5f*(z1.y + z2.y), Ki = 0.5f*(z2.x - z1.x);
        const float Pr = (Kr*Qr + Ki*Qi) * (1.f/32.f);
        const float Pi = (Ki*Qr - Kr*Qi) * (1.f/32.f);
        S1[k].x = Pr*V1[k].x - Pi*V1[k].y;
        S1[k].y = -(Pr*V1[k].y + Pi*V1[k].x);
    }

    // ---- FFT(q2 + i*k2) ; S2 = conj(K2*conj(Q2)*V2/32) ----
    #pragma unroll
    for (int k = 0; k < 4; ++k) {
        const int i = tid + 256*k;
        f32x2 t; t.x = (float)r2[i]; t.y = (float)r2[1024+i];
        X[PAD(i)] = t;
    }
    __syncthreads();
    fft1024r4(X, Y, tid);
    #pragma unroll
    for (int k = 0; k < 4; ++k) {
        const int f = tid + 256*k;
        const int g = (PD - f) & (PD-1);
        const f32x2 z1 = Y[PAD(f)], z2 = Y[PAD(g)];
        const float Qr = 0.5f*(z1.x + z2.x), Qi = 0.5f*(z1.y - z2.y);
        const float Kr = 0.5f*(z1.y + z2.y), Ki = 0.5f*(z2.x - z1.x);
        const float Pr = (Kr*Qr + Ki*Qi) * (1.f/32.f);
        const float Pi = (Ki*Qr - Kr*Qi) * (1.f/32.f);
        S2[k].x = Pr*V2[k].x - Pi*V2[k].y;
        S2[k].y = -(Pr*V2[k].y + Pi*V2[k].x);
    }

    // ---- packed inverse: FFT(S1 + i*S2) ----
    #pragma unroll
    for (int k = 0; k < 4; ++k) {
        const int f = tid + 256*k;
        f32x2 t; t.x = S1[k].x - S2[k].y; t.y = S1[k].y + S2[k].x;
        X[PAD(f)] = t;
    }
    __syncthreads();
    fft1024r4(X, Y, tid);
    f16* o1 = outg + row0*PD;
    f16* o2 = o1 + PD;
    #pragma unroll
    for (int k = 0; k < 4; ++k) {
        const int n = tid + 256*k;
        const f32x2 z = Y[PAD(n)];
        o1[n] = (f16)(z.x * (1.f/1024.f));
        o2[n] = (f16)(z.y * (1.f/1024.f));
    }
}

// ---------------------------------------------------------------------------
extern "C" void kernel_launch(void* const* d_in, const int* in_sizes, int n_in,
                              void* d_out, int out_size, void* d_ws, size_t ws_size,
                              hipStream_t stream)
{
    const float* x      = (const float*)d_in[0];
    const float* conv_w = (const float*)d_in[1];   // [L,E,1,K]
    const float* conv_b = (const float*)d_in[2];   // [L,E]
    const float* wq     = (const float*)d_in[3];   // [L,P,W]
    const float* bq     = (const float*)d_in[4];   // [L,P]
    const float* wk     = (const float*)d_in[5];
    const float* bk     = (const float*)d_in[6];
    const float* wv     = (const float*)d_in[7];
    const float* bv     = (const float*)d_in[8];
    const float* wo     = (const float*)d_in[9];   // [L,W,P]
    const float* bo     = (const float*)d_in[10];  // [L,W]

    // workspace layout (64 MiB), per-layer weight slots reused:
    //   0M..12M : wqkv16 f16 [3072, 2048]  (q rows 0-1023, k 1024-2047, v 2048-3071)
    //  12M..16M : wo16   f16 [2048, 1024]
    //  16M..40M : qkvbuf f16 [4096, 3072]  (row-interleaved q|k|v)
    //  40M..56M : xc16   f16 [4096, 2048]  (first 8 MiB also aliased wvr16 [4096,1024])
    //  56M..72M : xmid   f16 [4096, 2048]
    char* ws = (char*)d_ws;
    const size_t MB = 1024*1024;
    f16*   wqkv16 = (f16*)(ws);
    f16*   wo16   = (f16*)(ws + 12*MB);
    f16*   qkvbuf = (f16*)(ws + 16*MB);
    f16*   xc16   = (f16*)(ws + 40*MB);
    f16*   xmid   = (f16*)(ws + 56*MB);
    f16*   wvr16  = xc16;   // alias: xc dead once the QKV GEMM completes

    for (int l = 0; l < LN; ++l) {
        // convert this layer's 4 weight tensors in one dispatch
        cvt_layer<<<dim3(4*NWL/4/256), dim3(256), 0, stream>>>(
            wq + (size_t)l*NWL, wk + (size_t)l*NWL, wv + (size_t)l*NWL, wo + (size_t)l*NWL,
            wqkv16, wo16);

        if (l == 0)
            conv_moe<float><<<dim3(MROWS), dim3(256), 0, stream>>>(
                x, conv_w, conv_b, xc16);
        else
            conv_moe<f16><<<dim3(MROWS), dim3(256), 0, stream>>>(
                xmid, conv_w + (size_t)l*ED*KSZ, conv_b + (size_t)l*ED, xc16);

        // qkv = xc @ wqkv^T + [bq|bk|bv]   (M=4096, K=2048, N=3072), f16 out
        // 128x192 3-deep pipelined GEMM: grid 32x16 = 512 blocks (2 even rounds)
        gemmQKV<<<dim3((MROWS/128)*(QKVN/192)), dim3(512), 0, stream>>>(
            xc16, wqkv16,
            bq + (size_t)l*PD, bk + (size_t)l*PD, bv + (size_t)l*PD,
            qkvbuf, WD, QKVN);

        fft_attn2<<<dim3(MROWS/2), dim3(256), 0, stream>>>(qkvbuf, wvr16);

        // xnext = wvr @ wo^T + bo  (M=4096, K=1024, N=2048)
        if (l == LN-1)
            gemm_f16<float><<<dim3(MROWS/128, WD/128), dim3(256), 0, stream>>>(
                wvr16, wo16,
                bo + (size_t)l*WD, bo + (size_t)l*WD + PD, bo + (size_t)l*WD + PD,
                (float*)d_out, PD, WD);
        else
            gemm_f16<f16><<<dim3(MROWS/128, WD/128), dim3(256), 0, stream>>>(
                wvr16, wo16,
                bo + (size_t)l*WD, bo + (size_t)l*WD + PD, bo + (size_t)l*WD + PD,
                xmid, PD, WD);
    }
}

// Round 5
// 403.977 us; speedup vs baseline: 1.0985x; 1.0985x over previous
//
#include <hip/hip_runtime.h>
#include <hip/hip_bf16.h>

// Problem constants (FEDformerEncoder): BS=32 CNT=128 W=2048 P=1024 E=8 K=25 L=2
#define BSZ 32
#define CNTS 128
#define WD 2048
#define PD 1024
#define ED 8
#define KSZ 25
#define LN 2
#define MROWS (BSZ*CNTS)   // 4096
#define QKVN (3*PD)        // 3072
#define NWL (PD*WD)        // 2M elements per weight tensor per layer

typedef _Float16 f16;
typedef __attribute__((ext_vector_type(8))) _Float16 f16x8;  // 8 f16 = 4 VGPRs
typedef __attribute__((ext_vector_type(4))) float f32x4;
typedef __attribute__((ext_vector_type(2))) float f32x2;

#define PI_F 3.14159265358979323846f
// LDS physical index padding for the FFT (+1 float2 per 32 elements)
#define PAD(a) ((a) + ((a) >> 5))

// ---------------------------------------------------------------------------
// Per-layer weight conversion, one dispatch: wq|wk|wv -> wqkv16 packed, wo -> wo16.
// ---------------------------------------------------------------------------
__global__ __launch_bounds__(256) void cvt_layer(
    const float* __restrict__ wq, const float* __restrict__ wk,
    const float* __restrict__ wv, const float* __restrict__ wo,
    f16* __restrict__ wqkv16, f16* __restrict__ wo16)
{
    const int i = (blockIdx.x * 256 + threadIdx.x) * 4;
    const float* src;
    f16* dst;
    if (i < 3*NWL) {
        dst = wqkv16 + i;
        src = (i < NWL) ? wq + i : (i < 2*NWL) ? wk + (i - NWL) : wv + (i - 2*NWL);
    } else {
        dst = wo16 + (i - 3*NWL);
        src = wo + (i - 3*NWL);
    }
    const float4 v = *(const float4*)src;
    f16 o[4];
    o[0] = (f16)v.x; o[1] = (f16)v.y; o[2] = (f16)v.z; o[3] = (f16)v.w;
    *(ushort4*)dst = *(const ushort4*)o;
}

// ---------------------------------------------------------------------------
// MoE conv: mean over E of conv1d(x, w_e)+b_e == conv1d(x, mean_e w_e)+mean_e b_e
// Vectorized: 1 vector load/thread, 32-float register window, 8 outputs/thread,
// one f16x8 store (was: 2048 scalar f16 loads + 2048 scalar f16 stores/row).
// ---------------------------------------------------------------------------
template<typename IT>
__global__ __launch_bounds__(256) void conv_moe(
    const IT* __restrict__ xin,      // [4096, 2048]
    const float* __restrict__ cw,    // [E, K] layer slice
    const float* __restrict__ cb,    // [E]
    f16* __restrict__ xo)            // [4096, 2048] f16
{
    __shared__ float srow[WD];
    __shared__ float swb[KSZ];
    __shared__ float sbb;
    const int tid = threadIdx.x;
    const size_t row = blockIdx.x;
    if (tid < KSZ) {
        float s = 0.f;
        for (int e = 0; e < ED; ++e) s += cw[e*KSZ + tid];
        swb[tid] = s * (1.f/ED);
    }
    if (tid == 32) {
        float s = 0.f;
        for (int e = 0; e < ED; ++e) s += cb[e];
        sbb = s * (1.f/ED);
    }
    const IT* xr = xin + row*WD;
    // vector load: 8 elements/thread
    if constexpr (sizeof(IT) == 2) {
        const f16x8 v = *(const f16x8*)(xr + tid*8);
        #pragma unroll
        for (int j = 0; j < 8; ++j) srow[tid*8 + j] = (float)v[j];
    } else {
        const float4 v0 = *(const float4*)(xr + tid*8);
        const float4 v1 = *(const float4*)(xr + tid*8 + 4);
        srow[tid*8+0] = v0.x; srow[tid*8+1] = v0.y; srow[tid*8+2] = v0.z; srow[tid*8+3] = v0.w;
        srow[tid*8+4] = v1.x; srow[tid*8+5] = v1.y; srow[tid*8+6] = v1.z; srow[tid*8+7] = v1.w;
    }
    __syncthreads();
    const float bb = sbb;
    // register window: outputs tid*8 .. tid*8+7 need srow[tid*8-12 .. tid*8+19]
    float w[32];
    #pragma unroll
    for (int k = 0; k < 32; ++k) {
        const int idx = tid*8 + k - (KSZ/2);
        w[k] = (idx >= 0 && idx < WD) ? srow[idx] : 0.f;
    }
    f16 o[8];
    #pragma unroll
    for (int j = 0; j < 8; ++j) {
        float acc = bb;
        #pragma unroll
        for (int k = 0; k < KSZ; ++k) acc = fmaf(w[j+k], swb[k], acc);
        o[j] = (f16)acc;
    }
    *(f16x8*)(xo + row*WD + tid*8) = *(const f16x8*)o;
}

// ---------------------------------------------------------------------------
// f16 MFMA GEMM, B^T layout, 128x128 tile (verified m97-class structure).
// Kept for the out-projection GEMM (M=4096, K=1024, N=2048 -> 512 blocks).
// ---------------------------------------------------------------------------
template<typename OT>
__global__ __launch_bounds__(256, 2) void gemm_f16(
    const f16* __restrict__ A,   // [M, K]
    const f16* __restrict__ B,   // [N, K]
    const float* __restrict__ c0, const float* __restrict__ c1, const float* __restrict__ c2,
    OT* __restrict__ out,        // [M, N]
    const int K, const int N)
{
    __shared__ f16 sA[128*64];
    __shared__ f16 sB[128*64];
    const int tid  = threadIdx.x;
    const int m0   = blockIdx.x * 128;
    const int n0   = blockIdx.y * 128;
    const int lane = tid & 63;
    const int wave = tid >> 6;
    const int wm   = (wave >> 1) * 64;
    const int wn   = (wave & 1) * 64;
    const int quad = lane >> 4;
    const int r16  = lane & 15;

    f32x4 acc[4][4] = {};

    int aoff[4];
    #pragma unroll
    for (int t = 0; t < 4; ++t) {
        const int s = tid + 256*t;
        const int row = s >> 3;
        const int sc8 = ((s & 7) ^ (row & 7)) * 8;
        aoff[t] = row * K + sc8;
    }

    int aBase[4], aXor[4], bBase[4], bXor[4];
    #pragma unroll
    for (int i = 0; i < 4; ++i) {
        const int ra = wm + i*16 + r16;
        aBase[i] = ra << 3; aXor[i] = ra & 7;
        const int rb = wn + i*16 + r16;
        bBase[i] = rb << 3; bXor[i] = rb & 7;
    }

    const size_t mK = (size_t)m0 * K;
    const size_t nK = (size_t)n0 * K;

    for (int kb = 0; kb < K; kb += 64) {
        #pragma unroll
        for (int t = 0; t < 4; ++t) {
            const int s = tid + 256*t;
            __builtin_amdgcn_global_load_lds(
                (const __attribute__((address_space(1))) unsigned int*)(A + mK + aoff[t] + kb),
                (__attribute__((address_space(3))) unsigned int*)&sA[s*8], 16, 0, 0);
            __builtin_amdgcn_global_load_lds(
                (const __attribute__((address_space(1))) unsigned int*)(B + nK + aoff[t] + kb),
                (__attribute__((address_space(3))) unsigned int*)&sB[s*8], 16, 0, 0);
        }
        __syncthreads();

        #pragma unroll
        for (int ks = 0; ks < 2; ++ks) {
            const int c = ks*4 + quad;
            f16x8 af[4], bfm[4];
            #pragma unroll
            for (int i = 0; i < 4; ++i)
                af[i] = *(const f16x8*)&sA[(aBase[i] | (c ^ aXor[i])) * 8];
            #pragma unroll
            for (int j = 0; j < 4; ++j)
                bfm[j] = *(const f16x8*)&sB[(bBase[j] | (c ^ bXor[j])) * 8];
            #pragma unroll
            for (int i = 0; i < 4; ++i)
                #pragma unroll
                for (int j = 0; j < 4; ++j)
                    acc[i][j] = __builtin_amdgcn_mfma_f32_16x16x32_f16(af[i], bfm[j], acc[i][j], 0, 0, 0);
        }
        __syncthreads();
    }

    #pragma unroll
    for (int j = 0; j < 4; ++j) {
        const int col = n0 + wn + j*16 + r16;
        const float bv = (col < 1024) ? c0[col] : (col < 2048) ? c1[col-1024] : c2[col-2048];
        #pragma unroll
        for (int i = 0; i < 4; ++i) {
            #pragma unroll
            for (int r = 0; r < 4; ++r) {
                const int rowg = m0 + wm + i*16 + quad*4 + r;
                out[(size_t)rowg*N + col] = (OT)(acc[i][j][r] + bv);
            }
        }
    }
}

// ---------------------------------------------------------------------------
// 256x192 pipelined f16 GEMM for QKV (M=4096, K=2048, N=3072):
// grid 16m x 16n = 256 blocks. 512 thr = 8 waves (2M x 4N), per-wave 128x48.
// LDS 112 KiB; XOR-chunk swizzled; 4-barrier schedule with counted waits.
// (Best-measured QKV variant this session: 72 us, FETCH 41 MB, 0 conflicts.)
// ---------------------------------------------------------------------------
__global__ __launch_bounds__(512, 2) void gemm192(
    const f16* __restrict__ A,   // [M, K]
    const f16* __restrict__ B,   // [N, K]
    const float* __restrict__ c0, const float* __restrict__ c1, const float* __restrict__ c2,
    f16* __restrict__ out,       // [M, N]
    const int K, const int N)
{
    __shared__ __align__(16) f16 sA[2][2][128*64];
    __shared__ __align__(16) f16 sB[2][3][64*64];

    const int tid  = threadIdx.x;
    const int lane = tid & 63;
    const int wave = tid >> 6;
    const int wr   = wave >> 2;          // 0..1 : A 128-row half
    const int wc   = wave & 3;           // 0..3 : 48-col block
    const int quad = lane >> 4;
    const int r16  = lane & 15;
    const int xrA  = r16 & 7;            // A read-side XOR key

    // 2D XCD chunking: grid 16m x 16n = 256 blocks; XCD owns 4m x 8n (32 blocks)
    const int orig = blockIdx.x;
    const int xcd  = orig & 7;
    const int loc  = orig >> 3;          // 0..31
    const int mt   = (xcd >> 1) * 4 + (loc & 3);
    const int nt   = (xcd & 1) * 8 + (loc >> 2);
    const int m0   = mt * 256;
    const int n0   = nt * 192;

    f32x4 acc[8][3] = {};
    f16x8 bf[3][2];
    f16x8 aX0, aX1, aX2, aX3, aY0, aY1, aY2, aY3, aZ0, aZ1, aZ2, aZ3;

    int soffA[2];
    #pragma unroll
    for (int t = 0; t < 2; ++t) {
        const int s = tid + 512*t;
        const int row = s >> 3;
        soffA[t] = row * K + (((s & 7) ^ (row & 7)) * 8);
    }
    int soffB;
    {
        const int row = tid >> 3;
        soffB = row * K + (((tid & 7) ^ (row & 7)) * 8);
    }

    int bPiece[3], bBase[3], bXor[3];
    #pragma unroll
    for (int j = 0; j < 3; ++j) {
        const int rb = wc*48 + j*16 + r16;
        bPiece[j] = rb >> 6;
        bBase[j]  = (rb & 63) << 3;
        bXor[j]   = rb & 7;
    }

    const f16* Abase[2] = { A + (size_t)m0 * K, A + (size_t)(m0 + 128) * K };
    const f16* Bp[3]    = { B + (size_t)n0 * K, B + (size_t)(n0 + 64) * K,
                            B + (size_t)(n0 + 128) * K };

    #define STAGE_A(BUF, HALF, GOFF)                                              \
      { _Pragma("unroll") for (int t = 0; t < 2; ++t) {                           \
          __builtin_amdgcn_global_load_lds(                                       \
            (const __attribute__((address_space(1))) unsigned int*)(Abase[HALF] + soffA[t] + (GOFF)), \
            (__attribute__((address_space(3))) unsigned int*)&sA[BUF][HALF][(tid + 512*t)*8], \
            16, 0, 0); } }

    #define STAGE_B(BUF, PIECE, GOFF)                                             \
      { __builtin_amdgcn_global_load_lds(                                         \
          (const __attribute__((address_space(1))) unsigned int*)(Bp[PIECE] + soffB + (GOFF)), \
          (__attribute__((address_space(3))) unsigned int*)&sB[BUF][PIECE][tid*8], \
          16, 0, 0); }

    #define LDA(BUF, ROW, C) \
      (*(const f16x8*)&sA[BUF][wr][ (((ROW) << 3) + ((C) ^ xrA)) * 8 ])

    #define LDB(BUF, J, C) \
      (*(const f16x8*)&sB[BUF][bPiece[J]][ (bBase[J] + ((C) ^ bXor[J])) * 8 ])

    #define READ_BF(BUF)                                                          \
      { _Pragma("unroll") for (int j = 0; j < 3; ++j) {                           \
          bf[j][0] = LDB(BUF, j, quad);                                           \
          bf[j][1] = LDB(BUF, j, 4 + quad);                                       \
        } }

    #define READ_A(BUF, Q, D0, D1, D2, D3)                                        \
      D0 = LDA(BUF, (2*(Q))*16   + r16, quad);                                    \
      D1 = LDA(BUF, (2*(Q))*16   + r16, 4 + quad);                                \
      D2 = LDA(BUF, (2*(Q)+1)*16 + r16, quad);                                    \
      D3 = LDA(BUF, (2*(Q)+1)*16 + r16, 4 + quad);

    #define MFMA_Q(Q, D0, D1, D2, D3)                                             \
      __builtin_amdgcn_s_setprio(1);                                              \
      { _Pragma("unroll") for (int jj = 0; jj < 3; ++jj) {                        \
          acc[2*(Q)][jj]   = __builtin_amdgcn_mfma_f32_16x16x32_f16(D0, bf[jj][0], acc[2*(Q)][jj],   0,0,0); \
          acc[2*(Q)+1][jj] = __builtin_amdgcn_mfma_f32_16x16x32_f16(D2, bf[jj][0], acc[2*(Q)+1][jj], 0,0,0); \
        } }                                                                       \
      { _Pragma("unroll") for (int jj = 0; jj < 3; ++jj) {                        \
          acc[2*(Q)][jj]   = __builtin_amdgcn_mfma_f32_16x16x32_f16(D1, bf[jj][1], acc[2*(Q)][jj],   0,0,0); \
          acc[2*(Q)+1][jj] = __builtin_amdgcn_mfma_f32_16x16x32_f16(D3, bf[jj][1], acc[2*(Q)+1][jj], 0,0,0); \
        } }                                                                       \
      __builtin_amdgcn_s_setprio(0);

    #define LGKM(n) asm volatile("s_waitcnt lgkmcnt(" #n ")" ::: "memory");       \
                    __builtin_amdgcn_sched_barrier(0);
    #define VMC(n)  asm volatile("s_waitcnt vmcnt(" #n ")" ::: "memory");
    #define BAR()   __builtin_amdgcn_s_barrier();

    // prologue: B-buf0 (3), A-buf0 (4), B-buf1 (3) -> 10 loads; need oldest 7
    STAGE_B(0, 0, 0); STAGE_B(0, 1, 0); STAGE_B(0, 2, 0);
    STAGE_A(0, 0, 0); STAGE_A(0, 1, 0);
    STAGE_B(1, 0, 64); STAGE_B(1, 1, 64); STAGE_B(1, 2, 64);
    VMC(3)
    BAR()

    const int NIT = K >> 7;   // two K-tiles (BK=64) per iteration
    for (int it = 0; it < NIT; ++it) {
        const bool kl = (it == NIT - 1);
        const int kb1 = (2*it + 1) * 64;
        const int kb2 = kb1 + 64;
        const int kb3 = kb1 + 128;

        // ---------- K-tile 2it : buf0 ----------
        STAGE_A(1, 0, kb1);                                    // P1
        READ_BF(0)
        READ_A(0, 0, aX0, aX1, aX2, aX3)
        LGKM(0)
        MFMA_Q(0, aX0, aX1, aX2, aX3)
        BAR()                                                  // B1
        STAGE_A(1, 1, kb1);                                    // P2
        READ_A(0, 1, aY0, aY1, aY2, aY3)
        READ_A(0, 2, aZ0, aZ1, aZ2, aZ3)
        LGKM(4)
        MFMA_Q(1, aY0, aY1, aY2, aY3)
        if (!kl) { STAGE_B(0, 0, kb2); STAGE_B(0, 1, kb2); }   // P3
        READ_A(0, 3, aX0, aX1, aX2, aX3)
        LGKM(4)
        MFMA_Q(2, aZ0, aZ1, aZ2, aZ3)
        if (!kl) { STAGE_B(0, 2, kb2); }                       // P4
        LGKM(0)
        MFMA_Q(3, aX0, aX1, aX2, aX3)
        if (!kl) { VMC(3) } else { VMC(0) }
        BAR()                                                  // B2

        // ---------- K-tile 2it+1 : buf1 ----------
        if (!kl) STAGE_A(0, 0, kb2);                           // P5
        READ_BF(1)
        READ_A(1, 0, aX0, aX1, aX2, aX3)
        LGKM(0)
        MFMA_Q(0, aX0, aX1, aX2, aX3)
        BAR()                                                  // B3
        if (!kl) STAGE_A(0, 1, kb2);                           // P6
        READ_A(1, 1, aY0, aY1, aY2, aY3)
        READ_A(1, 2, aZ0, aZ1, aZ2, aZ3)
        LGKM(4)
        MFMA_Q(1, aY0, aY1, aY2, aY3)
        if (!kl) { STAGE_B(1, 0, kb3); STAGE_B(1, 1, kb3); }   // P7
        READ_A(1, 3, aX0, aX1, aX2, aX3)
        LGKM(4)
        MFMA_Q(2, aZ0, aZ1, aZ2, aZ3)
        if (!kl) { STAGE_B(1, 2, kb3); }                       // P8
        LGKM(0)
        MFMA_Q(3, aX0, aX1, aX2, aX3)
        if (!kl) { VMC(3) }
        BAR()                                                  // B4
    }

    // epilogue: C/D mapping (16x16x32): col = lane&15, row = quad*4 + r
    #pragma unroll
    for (int j = 0; j < 3; ++j) {
        const int col = n0 + wc*48 + j*16 + r16;
        const float bv = (col < 1024) ? c0[col] : (col < 2048) ? c1[col-1024] : c2[col-2048];
        #pragma unroll
        for (int mi = 0; mi < 8; ++mi) {
            #pragma unroll
            for (int r = 0; r < 4; ++r) {
                const int rowg = m0 + wr*128 + mi*16 + quad*4 + r;
                out[(size_t)rowg*N + col] = (f16)(acc[mi][j][r] + bv);
            }
        }
    }

    #undef STAGE_A
    #undef STAGE_B
    #undef LDA
    #undef LDB
    #undef READ_BF
    #undef READ_A
    #undef MFMA_Q
    #undef LGKM
    #undef VMC
    #undef BAR
}

// ---------------------------------------------------------------------------
// Stockham radix-4 DIF FFT, 1024 points, 256 threads, interleaved f32x2 in LDS.
// Twiddles hoisted: tws/twc[5] computed ONCE per thread by the caller (they
// depend only on tid & stage) -> 5 sincos/thread instead of 20.
// ---------------------------------------------------------------------------
__device__ inline void fft1024r4(f32x2* x, f32x2* y, const int tid,
                                 const float* tws, const float* twc)
{
    f32x2* src = x;
    f32x2* dst = y;
    #pragma unroll
    for (int st = 0; st < 5; ++st) {
        const int ls = 2*st;
        const int s  = 1 << ls;
        const int p  = tid >> ls;
        const int q  = tid & (s - 1);
        const f32x2 a = src[PAD(tid)];
        const f32x2 b = src[PAD(tid + 256)];
        const f32x2 c = src[PAD(tid + 512)];
        const f32x2 d = src[PAD(tid + 768)];
        const float ws = tws[st], wc = twc[st];
        const float apcx = a.x + c.x, apcy = a.y + c.y;
        const float amcx = a.x - c.x, amcy = a.y - c.y;
        const float bpdx = b.x + d.x, bpdy = b.y + d.y;
        const float bmdx = b.x - d.x, bmdy = b.y - d.y;
        f32x2 y0; y0.x = apcx + bpdx; y0.y = apcy + bpdy;
        const float t1x = amcx + bmdy, t1y = amcy - bmdx;   // amc - i*bmd
        const float t2x = apcx - bpdx, t2y = apcy - bpdy;
        const float t3x = amcx - bmdy, t3y = amcy + bmdx;   // amc + i*bmd
        const float w2x = wc*wc - ws*ws, w2y = 2.f*wc*ws;
        const float w3x = w2x*wc - w2y*ws, w3y = w2x*ws + w2y*wc;
        f32x2 y1; y1.x = wc*t1x - ws*t1y;   y1.y = wc*t1y + ws*t1x;
        f32x2 y2; y2.x = w2x*t2x - w2y*t2y; y2.y = w2x*t2y + w2y*t2x;
        f32x2 y3; y3.x = w3x*t3x - w3y*t3y; y3.y = w3x*t3y + w3y*t3x;
        const int base = q + ((p * s) << 2);
        dst[PAD(base)]       = y0;
        dst[PAD(base + s)]   = y1;
        dst[PAD(base + 2*s)] = y2;
        dst[PAD(base + 3*s)] = y3;
        __syncthreads();
        f32x2* t = src; src = dst; dst = t;
    }
}

// ---------------------------------------------------------------------------
// FFT-domain attention, two rows per block, packed-real FFTs (f16 in, f16 out).
// Inputs staged into LDS with 3 x f16x8 vector loads/thread (was 24 scalar
// f16 global loads/thread); twiddles hoisted (5 sincos/thread, was 20).
// ---------------------------------------------------------------------------
__global__ __launch_bounds__(256) void fft_attn2(
    const f16* __restrict__ qkv, f16* __restrict__ outg)
{
    __shared__ f32x2 X[PAD(1023)+1], Y[PAD(1023)+1];
    __shared__ f16 st[2*QKVN];              // 12 KiB: row1 q|k|v, row2 q|k|v
    const int tid = threadIdx.x;
    const size_t row0 = (size_t)blockIdx.x * 2;
    const f16* r1 = qkv + row0*QKVN;        // q1 | k1 | v1
    const f16* r2 = r1 + QKVN;              // q2 | k2 | v2

    // ---- stage both rows (6144 f16 = 768 chunks of 8; 3 chunks/thread) ----
    #pragma unroll
    for (int p = 0; p < 3; ++p) {
        const int c = tid + 256*p;          // 0..767
        const f16* src = (c < 384) ? (r1 + (c)*8) : (r2 + (c - 384)*8);
        *(f16x8*)&st[c*8] = *(const f16x8*)src;
    }

    // ---- hoisted twiddles: stage st, p = tid>>2st, n = 1024>>2st ----
    float tws[5], twc[5];
    #pragma unroll
    for (int s5 = 0; s5 < 5; ++s5) {
        const int ls = 2*s5;
        const int p  = tid >> ls;
        __sincosf(-2.f*PI_F * (float)p / (float)(1024 >> ls), &tws[s5], &twc[s5]);
    }
    __syncthreads();

    const f16* s1 = st;                     // row1 base
    const f16* s2 = st + QKVN;              // row2 base

    f32x2 V1[4], V2[4], S1[4], S2[4];

    // ---- FFT(v1 + i*v2) -> V1, V2 in registers ----
    #pragma unroll
    for (int k = 0; k < 4; ++k) {
        const int i = tid + 256*k;
        f32x2 t; t.x = (float)s1[2048+i]; t.y = (float)s2[2048+i];
        X[PAD(i)] = t;
    }
    __syncthreads();
    fft1024r4(X, Y, tid, tws, twc);
    #pragma unroll
    for (int k = 0; k < 4; ++k) {
        const int f = tid + 256*k;
        const int g = (PD - f) & (PD-1);
        const f32x2 z1 = Y[PAD(f)], z2 = Y[PAD(g)];
        V1[k].x = 0.5f*(z1.x + z2.x); V1[k].y = 0.5f*(z1.y - z2.y);
        V2[k].x = 0.5f*(z1.y + z2.y); V2[k].y = 0.5f*(z2.x - z1.x);
    }

    // ---- FFT(q1 + i*k1) ; S1 = conj(K1*conj(Q1)*V1/32) ----
    #pragma unroll
    for (int k = 0; k < 4; ++k) {
        const int i = tid + 256*k;
        f32x2 t; t.x = (float)s1[i]; t.y = (float)s1[1024+i];
        X[PAD(i)] = t;
    }
    __syncthreads();   // fences the V-split reads of Y above
    fft1024r4(X, Y, tid, tws, twc);
    #pragma unroll
    for (int k = 0; k < 4; ++k) {
        const int f = tid + 256*k;
        const int g = (PD - f) & (PD-1);
        const f32x2 z1 = Y[PAD(f)], z2 = Y[PAD(g)];
        const float Qr = 0.5f*(z1.x + z2.x), Qi = 0.5f*(z1.y - z2.y);
        const float Kr = 0.5f*(z1.y + z2.y), Ki = 0.5f*(z2.x - z1.x);
        const float Pr = (Kr*Qr + Ki*Qi) * (1.f/32.f);
        const float Pi = (Ki*Qr - Kr*Qi) * (1.f/32.f);
        S1[k].x = Pr*V1[k].x - Pi*V1[k].y;
        S1[k].y = -(Pr*V1[k].y + Pi*V1[k].x);
    }

    // ---- FFT(q2 + i*k2) ; S2 = conj(K2*conj(Q2)*V2/32) ----
    #pragma unroll
    for (int k = 0; k < 4; ++k) {
        const int i = tid + 256*k;
        f32x2 t; t.x = (float)s2[i]; t.y = (float)s2[1024+i];
        X[PAD(i)] = t;
    }
    __syncthreads();
    fft1024r4(X, Y, tid, tws, twc);
    #pragma unroll
    for (int k = 0; k < 4; ++k) {
        const int f = tid + 256*k;
        const int g = (PD - f) & (PD-1);
        const f32x2 z1 = Y[PAD(f)], z2 = Y[PAD(g)];
        const float Qr = 0.5f*(z1.x + z2.x), Qi = 0.5f*(z1.y - z2.y);
        const float Kr = 0.5f*(z1.y + z2.y), Ki = 0.5f*(z2.x - z1.x);
        const float Pr = (Kr*Qr + Ki*Qi) * (1.f/32.f);
        const float Pi = (Ki*Qr - Kr*Qi) * (1.f/32.f);
        S2[k].x = Pr*V2[k].x - Pi*V2[k].y;
        S2[k].y = -(Pr*V2[k].y + Pi*V2[k].x);
    }

    // ---- packed inverse: FFT(S1 + i*S2) ----
    #pragma unroll
    for (int k = 0; k < 4; ++k) {
        const int f = tid + 256*k;
        f32x2 t; t.x = S1[k].x - S2[k].y; t.y = S1[k].y + S2[k].x;
        X[PAD(f)] = t;
    }
    __syncthreads();
    fft1024r4(X, Y, tid, tws, twc);
    f16* o1 = outg + row0*PD;
    f16* o2 = o1 + PD;
    #pragma unroll
    for (int k = 0; k < 4; ++k) {
        const int n = tid + 256*k;
        const f32x2 z = Y[PAD(n)];
        o1[n] = (f16)(z.x * (1.f/1024.f));
        o2[n] = (f16)(z.y * (1.f/1024.f));
    }
}

// ---------------------------------------------------------------------------
extern "C" void kernel_launch(void* const* d_in, const int* in_sizes, int n_in,
                              void* d_out, int out_size, void* d_ws, size_t ws_size,
                              hipStream_t stream)
{
    const float* x      = (const float*)d_in[0];
    const float* conv_w = (const float*)d_in[1];   // [L,E,1,K]
    const float* conv_b = (const float*)d_in[2];   // [L,E]
    const float* wq     = (const float*)d_in[3];   // [L,P,W]
    const float* bq     = (const float*)d_in[4];   // [L,P]
    const float* wk     = (const float*)d_in[5];
    const float* bk     = (const float*)d_in[6];
    const float* wv     = (const float*)d_in[7];
    const float* bv     = (const float*)d_in[8];
    const float* wo     = (const float*)d_in[9];   // [L,W,P]
    const float* bo     = (const float*)d_in[10];  // [L,W]

    // workspace layout, per-layer weight slots reused:
    //   0M..12M : wqkv16 f16 [3072, 2048]  (q rows 0-1023, k 1024-2047, v 2048-3071)
    //  12M..16M : wo16   f16 [2048, 1024]
    //  16M..40M : qkvbuf f16 [4096, 3072]  (row-interleaved q|k|v)
    //  40M..56M : xc16   f16 [4096, 2048]  (first 8 MiB also aliased wvr16 [4096,1024])
    //  56M..72M : xmid   f16 [4096, 2048]
    char* ws = (char*)d_ws;
    const size_t MB = 1024*1024;
    f16*   wqkv16 = (f16*)(ws);
    f16*   wo16   = (f16*)(ws + 12*MB);
    f16*   qkvbuf = (f16*)(ws + 16*MB);
    f16*   xc16   = (f16*)(ws + 40*MB);
    f16*   xmid   = (f16*)(ws + 56*MB);
    f16*   wvr16  = xc16;   // alias: xc dead once the QKV GEMM completes

    for (int l = 0; l < LN; ++l) {
        // convert this layer's 4 weight tensors in one dispatch
        cvt_layer<<<dim3(4*NWL/4/256), dim3(256), 0, stream>>>(
            wq + (size_t)l*NWL, wk + (size_t)l*NWL, wv + (size_t)l*NWL, wo + (size_t)l*NWL,
            wqkv16, wo16);

        if (l == 0)
            conv_moe<float><<<dim3(MROWS), dim3(256), 0, stream>>>(
                x, conv_w, conv_b, xc16);
        else
            conv_moe<f16><<<dim3(MROWS), dim3(256), 0, stream>>>(
                xmid, conv_w + (size_t)l*ED*KSZ, conv_b + (size_t)l*ED, xc16);

        // qkv = xc @ wqkv^T + [bq|bk|bv]   (M=4096, K=2048, N=3072), f16 out
        gemm192<<<dim3((MROWS/256)*(QKVN/192)), dim3(512), 0, stream>>>(
            xc16, wqkv16,
            bq + (size_t)l*PD, bk + (size_t)l*PD, bv + (size_t)l*PD,
            qkvbuf, WD, QKVN);

        fft_attn2<<<dim3(MROWS/2), dim3(256), 0, stream>>>(qkvbuf, wvr16);

        // xnext = wvr @ wo^T + bo  (M=4096, K=1024, N=2048)
        if (l == LN-1)
            gemm_f16<float><<<dim3(MROWS/128, WD/128), dim3(256), 0, stream>>>(
                wvr16, wo16,
                bo + (size_t)l*WD, bo + (size_t)l*WD + PD, bo + (size_t)l*WD + PD,
                (float*)d_out, PD, WD);
        else
            gemm_f16<f16><<<dim3(MROWS/128, WD/128), dim3(256), 0, stream>>>(
                wvr16, wo16,
                bo + (size_t)l*WD, bo + (size_t)l*WD + PD, bo + (size_t)l*WD + PD,
                xmid, PD, WD);
    }
}